// Round 1
// baseline (69.416 us; speedup 1.0000x reference)
//
#include <hip/hip_runtime.h>

#define BATCH 16
#define CH 64
#define NGROUPS 8
#define CPG 8            // channels per group
#define HWPIX (128*128)  // pixels per channel
#define DD 2
#define EPSV 1e-5f
#define SPLIT 4          // blocks per channel (stats pass)
#define SPLITN 4         // blocks per channel (normalize pass)
#define TPB 256

// floats per channel = HWPIX*DD = 32768 ; float4 per channel = 8192
// float4 per split-chunk = 8192/SPLIT = 2048 ; per thread = 2048/256 = 8

__global__ __launch_bounds__(TPB) void gn_stats(const float* __restrict__ x,
                                                float* __restrict__ partials) {
    const int blk = blockIdx.x;
    const int sp  = blk % SPLIT;
    const int bc  = blk / SPLIT;              // b*CH + c
    const int F4_PER_CH = HWPIX * DD / 4;     // 8192
    const int CHUNK     = F4_PER_CH / SPLIT;  // 2048
    const float4* base = (const float4*)x + (size_t)bc * F4_PER_CH + (size_t)sp * CHUNK;
    const int tid = threadIdx.x;

    float s0 = 0.f, s1 = 0.f, sxx = 0.f, sxy = 0.f, syy = 0.f;
    const int PER_THREAD = CHUNK / TPB;       // 8
#pragma unroll
    for (int i = 0; i < PER_THREAD; ++i) {
        float4 v = base[tid + i * TPB];
        s0 += v.x + v.z;
        s1 += v.y + v.w;
        sxx = fmaf(v.x, v.x, fmaf(v.z, v.z, sxx));
        sxy = fmaf(v.x, v.y, fmaf(v.z, v.w, sxy));
        syy = fmaf(v.y, v.y, fmaf(v.w, v.w, syy));
    }
    // wave (64-lane) reduction
#pragma unroll
    for (int off = 32; off > 0; off >>= 1) {
        s0  += __shfl_down(s0, off);
        s1  += __shfl_down(s1, off);
        sxx += __shfl_down(sxx, off);
        sxy += __shfl_down(sxy, off);
        syy += __shfl_down(syy, off);
    }
    __shared__ float red[4][5];
    const int wave = tid >> 6, lane = tid & 63;
    if (lane == 0) {
        red[wave][0] = s0; red[wave][1] = s1; red[wave][2] = sxx;
        red[wave][3] = sxy; red[wave][4] = syy;
    }
    __syncthreads();
    if (tid == 0) {
        float r0 = 0.f, r1 = 0.f, r2 = 0.f, r3 = 0.f, r4 = 0.f;
#pragma unroll
        for (int w = 0; w < 4; ++w) {
            r0 += red[w][0]; r1 += red[w][1]; r2 += red[w][2];
            r3 += red[w][3]; r4 += red[w][4];
        }
        float* p = partials + (size_t)(bc * SPLIT + sp) * 5;
        p[0] = r0; p[1] = r1; p[2] = r2; p[3] = r3; p[4] = r4;
    }
}

// solved[b*NGROUPS+g] = {m0, m1, w00, w01, w11};  mv[b*CH+c] = {mv0, mv1}
__global__ void gn_solve(const float* __restrict__ partials,
                         float* __restrict__ solved,
                         float* __restrict__ mv) {
    const int tid = blockIdx.x * blockDim.x + threadIdx.x;
    if (tid < BATCH * CH) {
        float m0 = 0.f, m1 = 0.f;
#pragma unroll
        for (int s = 0; s < SPLIT; ++s) {
            const float* p = partials + ((size_t)tid * SPLIT + s) * 5;
            m0 += p[0]; m1 += p[1];
        }
        mv[tid * 2 + 0] = m0 / (float)HWPIX;
        mv[tid * 2 + 1] = m1 / (float)HWPIX;
    }
    if (tid < BATCH * NGROUPS) {
        const int b = tid / NGROUPS, g = tid % NGROUPS;
        float S0 = 0.f, S1 = 0.f, Sxx = 0.f, Sxy = 0.f, Syy = 0.f;
        for (int c = 0; c < CPG; ++c) {
            const int ch = b * CH + g * CPG + c;
#pragma unroll
            for (int s = 0; s < SPLIT; ++s) {
                const float* p = partials + ((size_t)ch * SPLIT + s) * 5;
                S0 += p[0]; S1 += p[1]; Sxx += p[2]; Sxy += p[3]; Syy += p[4];
            }
        }
        const float n = (float)(CPG * HWPIX);
        const float m0 = S0 / n, m1 = S1 / n;
        // cov + eps*I
        const float a  = Sxx / n - m0 * m0 + EPSV;
        const float bq = Sxy / n - m0 * m1;
        const float cc = Syy / n - m1 * m1 + EPSV;
        // closed-form (A)^(-1/2) for 2x2 SPD A: adj(A + s*I)/(s*t)
        const float det  = a * cc - bq * bq;
        const float sdet = sqrtf(det);
        const float t    = sqrtf(a + cc + 2.0f * sdet);
        const float inv  = 1.0f / (sdet * t);
        float* so = solved + (size_t)tid * 5;
        so[0] = m0;
        so[1] = m1;
        so[2] = (cc + sdet) * inv;   // w00
        so[3] = -bq * inv;           // w01 = w10
        so[4] = (a + sdet) * inv;    // w11
    }
}

__global__ __launch_bounds__(TPB) void gn_norm(const float* __restrict__ x,
                                               const float* __restrict__ solved,
                                               const float* __restrict__ mv,
                                               const float* __restrict__ scale,
                                               const float* __restrict__ bias,
                                               float* __restrict__ out) {
    const int blk = blockIdx.x;
    const int sp  = blk % SPLITN;
    const int bc  = blk / SPLITN;   // b*CH + c
    const int c   = bc % CH;
    const int b   = bc / CH;
    const int g   = c / CPG;

    const float* so = solved + (size_t)(b * NGROUPS + g) * 5;
    const float m0 = so[0], m1 = so[1];
    const float w00 = so[2], w01 = so[3], w11 = so[4];
    const float sc = scale[c], bi = bias[c];
    const float mv0 = mv[bc * 2 + 0], mv1 = mv[bc * 2 + 1];

    const float a00 = sc * w00, a01 = sc * w01, a11 = sc * w11;
    const float add0 = fmaf(bi, mv0, -(a00 * m0 + a01 * m1));
    const float add1 = fmaf(bi, mv1, -(a01 * m0 + a11 * m1));

    const int F4_PER_CH = HWPIX * DD / 4;      // 8192
    const int CHUNK     = F4_PER_CH / SPLITN;  // 2048
    const float4* src = (const float4*)x   + (size_t)bc * F4_PER_CH + (size_t)sp * CHUNK;
    float4*       dst = (float4*)out       + (size_t)bc * F4_PER_CH + (size_t)sp * CHUNK;
    const int tid = threadIdx.x;
    const int PER_THREAD = CHUNK / TPB;        // 8
#pragma unroll
    for (int i = 0; i < PER_THREAD; ++i) {
        float4 v = src[tid + i * TPB];
        float4 o;
        o.x = fmaf(a00, v.x, fmaf(a01, v.y, add0));
        o.y = fmaf(a01, v.x, fmaf(a11, v.y, add1));
        o.z = fmaf(a00, v.z, fmaf(a01, v.w, add0));
        o.w = fmaf(a01, v.z, fmaf(a11, v.w, add1));
        dst[tid + i * TPB] = o;
    }
}

extern "C" void kernel_launch(void* const* d_in, const int* in_sizes, int n_in,
                              void* d_out, int out_size, void* d_ws, size_t ws_size,
                              hipStream_t stream) {
    const float* x     = (const float*)d_in[0];
    const float* scale = (const float*)d_in[1];
    const float* bias  = (const float*)d_in[2];
    float* out = (float*)d_out;

    float* partials = (float*)d_ws;                        // 16*64*4*5 = 20480 floats
    float* solved   = partials + BATCH * CH * SPLIT * 5;   // 16*8*5  = 640 floats
    float* mv       = solved + BATCH * NGROUPS * 5;        // 16*64*2 = 2048 floats

    gn_stats<<<BATCH * CH * SPLIT, TPB, 0, stream>>>(x, partials);
    gn_solve<<<(BATCH * CH + 255) / 256, 256, 0, stream>>>(partials, solved, mv);
    gn_norm<<<BATCH * CH * SPLITN, TPB, 0, stream>>>(x, solved, mv, scale, bias, out);
}

// Round 3
// 64.387 us; speedup vs baseline: 1.0781x; 1.0781x over previous
//
#include <hip/hip_runtime.h>

#define BATCH 16
#define CH 64
#define NGROUPS 8
#define CPG 8            // channels per group
#define HWPIX (128*128)  // pixels per channel
#define DD 2
#define EPSV 1e-5f
#define SPLIT 4          // blocks per channel (stats pass)
#define SPLITN 4         // blocks per channel (normalize pass)
#define TPB 256

typedef float fx4 __attribute__((ext_vector_type(4)));  // native vec for nt-store

// floats per channel = HWPIX*DD = 32768 ; float4 per channel = 8192
// float4 per split-chunk = 8192/SPLIT = 2048 ; per thread = 2048/256 = 8

__global__ __launch_bounds__(TPB) void gn_stats(const float* __restrict__ x,
                                                float* __restrict__ partials) {
    const int blk = blockIdx.x;
    const int sp  = blk % SPLIT;
    const int bc  = blk / SPLIT;              // b*CH + c
    const int F4_PER_CH = HWPIX * DD / 4;     // 8192
    const int CHUNK     = F4_PER_CH / SPLIT;  // 2048
    const fx4* base = (const fx4*)x + (size_t)bc * F4_PER_CH + (size_t)sp * CHUNK;
    const int tid = threadIdx.x;

    float s0 = 0.f, s1 = 0.f, sxx = 0.f, sxy = 0.f, syy = 0.f;
    const int PER_THREAD = CHUNK / TPB;       // 8
#pragma unroll
    for (int i = 0; i < PER_THREAD; ++i) {
        fx4 v = base[tid + i * TPB];
        s0 += v.x + v.z;
        s1 += v.y + v.w;
        sxx = fmaf(v.x, v.x, fmaf(v.z, v.z, sxx));
        sxy = fmaf(v.x, v.y, fmaf(v.z, v.w, sxy));
        syy = fmaf(v.y, v.y, fmaf(v.w, v.w, syy));
    }
    // wave (64-lane) reduction
#pragma unroll
    for (int off = 32; off > 0; off >>= 1) {
        s0  += __shfl_down(s0, off);
        s1  += __shfl_down(s1, off);
        sxx += __shfl_down(sxx, off);
        sxy += __shfl_down(sxy, off);
        syy += __shfl_down(syy, off);
    }
    __shared__ float red[4][5];
    const int wave = tid >> 6, lane = tid & 63;
    if (lane == 0) {
        red[wave][0] = s0; red[wave][1] = s1; red[wave][2] = sxx;
        red[wave][3] = sxy; red[wave][4] = syy;
    }
    __syncthreads();
    if (tid == 0) {
        float r0 = 0.f, r1 = 0.f, r2 = 0.f, r3 = 0.f, r4 = 0.f;
#pragma unroll
        for (int w = 0; w < 4; ++w) {
            r0 += red[w][0]; r1 += red[w][1]; r2 += red[w][2];
            r3 += red[w][3]; r4 += red[w][4];
        }
        float* p = partials + (size_t)(bc * SPLIT + sp) * 5;
        p[0] = r0; p[1] = r1; p[2] = r2; p[3] = r3; p[4] = r4;
    }
}

// norm with inlined per-block solve: wave 0 reduces the group's 32 partial
// records (one per lane, 32-wide xor-shuffle) while the x loads are in flight.
__global__ __launch_bounds__(TPB) void gn_norm(const float* __restrict__ x,
                                               const float* __restrict__ partials,
                                               const float* __restrict__ scale,
                                               const float* __restrict__ bias,
                                               float* __restrict__ out) {
    const int blk = blockIdx.x;
    const int sp  = blk % SPLITN;
    const int bc  = blk / SPLITN;   // b*CH + c
    const int c   = bc % CH;
    const int b   = bc / CH;
    const int g   = c / CPG;
    const int cig = c % CPG;        // channel index within group

    const int F4_PER_CH = HWPIX * DD / 4;      // 8192
    const int CHUNK     = F4_PER_CH / SPLITN;  // 2048
    const fx4* src = (const fx4*)x + (size_t)bc * F4_PER_CH + (size_t)sp * CHUNK;
    fx4*       dst = (fx4*)out     + (size_t)bc * F4_PER_CH + (size_t)sp * CHUNK;
    const int tid = threadIdx.x;
    const int PER_THREAD = CHUNK / TPB;        // 8

    // issue the bulk loads first; solve latency hides under them
    fx4 v[PER_THREAD];
#pragma unroll
    for (int i = 0; i < PER_THREAD; ++i) v[i] = src[tid + i * TPB];

    __shared__ float coef[5];  // a00, a01, a11, add0, add1
    if (tid < 32) {
        // lane l -> group-channel l>>2, split l&3
        const float* p = partials +
            ((size_t)(b * CH + g * CPG + (tid >> 2)) * SPLIT + (tid & 3)) * 5;
        float p0 = p[0], p1 = p[1], p2 = p[2], p3 = p[3], p4 = p[4];
        const bool mine = (tid >> 2) == cig;   // records of this block's channel
        float q0 = mine ? p0 : 0.f, q1 = mine ? p1 : 0.f;
#pragma unroll
        for (int off = 16; off > 0; off >>= 1) {
            p0 += __shfl_xor(p0, off, 32);
            p1 += __shfl_xor(p1, off, 32);
            p2 += __shfl_xor(p2, off, 32);
            p3 += __shfl_xor(p3, off, 32);
            p4 += __shfl_xor(p4, off, 32);
            q0 += __shfl_xor(q0, off, 32);
            q1 += __shfl_xor(q1, off, 32);
        }
        if (tid == 0) {
            const float n  = (float)(CPG * HWPIX);
            const float m0 = p0 / n, m1 = p1 / n;
            const float a  = p2 / n - m0 * m0 + EPSV;
            const float bq = p3 / n - m0 * m1;
            const float cc = p4 / n - m1 * m1 + EPSV;
            const float sdet = sqrtf(a * cc - bq * bq);
            const float t    = sqrtf(a + cc + 2.0f * sdet);
            const float inv  = 1.0f / (sdet * t);
            const float w00 = (cc + sdet) * inv;
            const float w01 = -bq * inv;
            const float w11 = (a + sdet) * inv;
            const float sc = scale[c], bi = bias[c];
            const float mv0 = q0 / (float)HWPIX, mv1 = q1 / (float)HWPIX;
            const float a00 = sc * w00, a01 = sc * w01, a11 = sc * w11;
            coef[0] = a00;
            coef[1] = a01;
            coef[2] = a11;
            coef[3] = fmaf(bi, mv0, -(a00 * m0 + a01 * m1));
            coef[4] = fmaf(bi, mv1, -(a01 * m0 + a11 * m1));
        }
    }
    __syncthreads();
    const float a00 = coef[0], a01 = coef[1], a11 = coef[2];
    const float add0 = coef[3], add1 = coef[4];

#pragma unroll
    for (int i = 0; i < PER_THREAD; ++i) {
        fx4 o;
        o.x = fmaf(a00, v[i].x, fmaf(a01, v[i].y, add0));
        o.y = fmaf(a01, v[i].x, fmaf(a11, v[i].y, add1));
        o.z = fmaf(a00, v[i].z, fmaf(a01, v[i].w, add0));
        o.w = fmaf(a01, v[i].z, fmaf(a11, v[i].w, add1));
        __builtin_nontemporal_store(o, &dst[tid + i * TPB]);
    }
}

extern "C" void kernel_launch(void* const* d_in, const int* in_sizes, int n_in,
                              void* d_out, int out_size, void* d_ws, size_t ws_size,
                              hipStream_t stream) {
    const float* x     = (const float*)d_in[0];
    const float* scale = (const float*)d_in[1];
    const float* bias  = (const float*)d_in[2];
    float* out = (float*)d_out;

    float* partials = (float*)d_ws;   // 16*64*4*5 = 20480 floats

    gn_stats<<<BATCH * CH * SPLIT, TPB, 0, stream>>>(x, partials);
    gn_norm<<<BATCH * CH * SPLITN, TPB, 0, stream>>>(x, partials, scale, bias, out);
}

// Round 5
// 64.147 us; speedup vs baseline: 1.0821x; 1.0037x over previous
//
#include <hip/hip_runtime.h>
#include <hip/hip_cooperative_groups.h>

namespace cg = cooperative_groups;

#define BATCH 16
#define CH 64
#define NGROUPS 8
#define CPG 8                  // channels per group
#define HWPIX (128*128)        // pixels per channel
#define EPSV 1e-5f
#define TPB 256
#define F4_PER_CH (HWPIX*2/4)  // 8192 float4 per channel
#define ITERS (F4_PER_CH/TPB)  // 32 float4 per thread per channel
#define NBLK2 (BATCH*CH/2)     // 512 coop blocks, 2 channels each
#define REGI 20                // fx4 cached in registers per channel
#define LDSI 8                 // fx4 cached in LDS per channel
#define SPLIT 4                // fallback: blocks per channel

typedef float fx4 __attribute__((ext_vector_type(4)));

__device__ __forceinline__ void acc5(float& s0, float& s1, float& sxx,
                                     float& sxy, float& syy, fx4 t) {
    s0 += t.x + t.z;
    s1 += t.y + t.w;
    sxx = fmaf(t.x, t.x, fmaf(t.z, t.z, sxx));
    sxy = fmaf(t.x, t.y, fmaf(t.z, t.w, sxy));
    syy = fmaf(t.y, t.y, fmaf(t.w, t.w, syy));
}

__device__ __forceinline__ fx4 affine2(fx4 t, float a00, float a01, float a11,
                                       float d0, float d1) {
    fx4 o;
    o.x = fmaf(a00, t.x, fmaf(a01, t.y, d0));
    o.y = fmaf(a01, t.x, fmaf(a11, t.y, d1));
    o.z = fmaf(a00, t.z, fmaf(a01, t.w, d0));
    o.w = fmaf(a01, t.z, fmaf(a11, t.w, d1));
    return o;
}

// closed-form A^(-1/2) for 2x2 SPD A = cov + eps*I
__device__ __forceinline__ void solve_w(float p0, float p1, float p2, float p3,
                                        float p4, float n, float& m0, float& m1,
                                        float& w00, float& w01, float& w11) {
    m0 = p0 / n; m1 = p1 / n;
    const float a  = p2 / n - m0 * m0 + EPSV;
    const float bq = p3 / n - m0 * m1;
    const float cc = p4 / n - m1 * m1 + EPSV;
    const float sdet = sqrtf(a * cc - bq * bq);
    const float t    = sqrtf(a + cc + 2.0f * sdet);
    const float inv  = 1.0f / (sdet * t);
    w00 = (cc + sdet) * inv;
    w01 = -bq * inv;
    w11 = (a + sdet) * inv;
}

// ---------------- fused cooperative kernel: 512 blocks, 2 channels/block ----
// phase1 stats (cache 20 fx4/ch in regs + 8 fx4/ch in LDS) -> grid.sync ->
// solve 2x2 -> phase2 normalize (only 4/32 iters re-read, L3-resident).
__global__ __launch_bounds__(TPB, 2) void gn_fused2(const float* __restrict__ x,
                                                    const float* __restrict__ scale,
                                                    const float* __restrict__ bias,
                                                    float* __restrict__ partials,
                                                    float* __restrict__ out) {
    const int blk = blockIdx.x;
    const int chA = 2 * blk;          // global channel index
    const int cA  = chA % CH;         // channel within batch (cB = cA+1, same group)
    const int b   = chA / CH;
    const int g   = cA / CPG;
    const int tid = threadIdx.x;

    const fx4* srcA = (const fx4*)x + (size_t)chA * F4_PER_CH;
    const fx4* srcB = srcA + F4_PER_CH;

    __shared__ fx4 lcache[2 * LDSI * TPB];   // 64 KiB, per-thread slots
    __shared__ float red[4][10];
    __shared__ float own[4];                 // chA s0,s1 ; chB s0,s1
    __shared__ float coef[10];               // A: a00,a01,a11,d0,d1 ; B: same

    float A0 = 0.f, A1 = 0.f, Axx = 0.f, Axy = 0.f, Ayy = 0.f;
    float B0 = 0.f, B1 = 0.f, Bxx = 0.f, Bxy = 0.f, Byy = 0.f;
    fx4 va[REGI], vb[REGI];

    // ---- phase 1: stats + cache ----
#pragma unroll
    for (int i = 0; i < REGI; ++i) {
        fx4 t = __builtin_nontemporal_load(&srcA[i * TPB + tid]);
        va[i] = t; acc5(A0, A1, Axx, Axy, Ayy, t);
    }
#pragma unroll
    for (int i = 0; i < LDSI; ++i) {
        fx4 t = __builtin_nontemporal_load(&srcA[(REGI + i) * TPB + tid]);
        lcache[i * TPB + tid] = t; acc5(A0, A1, Axx, Axy, Ayy, t);
    }
#pragma unroll
    for (int i = REGI + LDSI; i < ITERS; ++i) {   // re-read in phase 2: normal load
        fx4 t = srcA[i * TPB + tid];
        acc5(A0, A1, Axx, Axy, Ayy, t);
    }
#pragma unroll
    for (int i = 0; i < REGI; ++i) {
        fx4 t = __builtin_nontemporal_load(&srcB[i * TPB + tid]);
        vb[i] = t; acc5(B0, B1, Bxx, Bxy, Byy, t);
    }
#pragma unroll
    for (int i = 0; i < LDSI; ++i) {
        fx4 t = __builtin_nontemporal_load(&srcB[(REGI + i) * TPB + tid]);
        lcache[(LDSI + i) * TPB + tid] = t; acc5(B0, B1, Bxx, Bxy, Byy, t);
    }
#pragma unroll
    for (int i = REGI + LDSI; i < ITERS; ++i) {
        fx4 t = srcB[i * TPB + tid];
        acc5(B0, B1, Bxx, Bxy, Byy, t);
    }

    // ---- block reduce (10 values) ----
#pragma unroll
    for (int off = 32; off > 0; off >>= 1) {
        A0 += __shfl_down(A0, off);  A1 += __shfl_down(A1, off);
        Axx += __shfl_down(Axx, off); Axy += __shfl_down(Axy, off);
        Ayy += __shfl_down(Ayy, off);
        B0 += __shfl_down(B0, off);  B1 += __shfl_down(B1, off);
        Bxx += __shfl_down(Bxx, off); Bxy += __shfl_down(Bxy, off);
        Byy += __shfl_down(Byy, off);
    }
    if ((tid & 63) == 0) {
        const int w = tid >> 6;
        red[w][0] = A0; red[w][1] = A1; red[w][2] = Axx; red[w][3] = Axy; red[w][4] = Ayy;
        red[w][5] = B0; red[w][6] = B1; red[w][7] = Bxx; red[w][8] = Bxy; red[w][9] = Byy;
    }
    __syncthreads();
    if (tid == 0) {
        float r[10];
#pragma unroll
        for (int k = 0; k < 10; ++k)
            r[k] = red[0][k] + red[1][k] + red[2][k] + red[3][k];
        float* pA = partials + (size_t)chA * 5;
        pA[0] = r[0]; pA[1] = r[1]; pA[2] = r[2]; pA[3] = r[3]; pA[4] = r[4];
        float* pB = partials + (size_t)(chA + 1) * 5;
        pB[0] = r[5]; pB[1] = r[6]; pB[2] = r[7]; pB[3] = r[8]; pB[4] = r[9];
        own[0] = r[0]; own[1] = r[1]; own[2] = r[5]; own[3] = r[6];
    }

    // ---- grid-wide barrier ----
    cg::this_grid().sync();

    // ---- solve: 8 lanes gather the group's 8 channel records ----
    if (tid < 8) {
        const float* p = partials + (size_t)(b * CH + g * CPG + tid) * 5;
        float p0 = p[0], p1 = p[1], p2 = p[2], p3 = p[3], p4 = p[4];
#pragma unroll
        for (int off = 4; off > 0; off >>= 1) {
            p0 += __shfl_xor(p0, off, 8);
            p1 += __shfl_xor(p1, off, 8);
            p2 += __shfl_xor(p2, off, 8);
            p3 += __shfl_xor(p3, off, 8);
            p4 += __shfl_xor(p4, off, 8);
        }
        if (tid == 0) {
            float m0, m1, w00, w01, w11;
            solve_w(p0, p1, p2, p3, p4, (float)(CPG * HWPIX), m0, m1, w00, w01, w11);
            const float scA = scale[cA], biA = bias[cA];
            const float scB = scale[cA + 1], biB = bias[cA + 1];
            const float aA00 = scA * w00, aA01 = scA * w01, aA11 = scA * w11;
            const float aB00 = scB * w00, aB01 = scB * w01, aB11 = scB * w11;
            coef[0] = aA00; coef[1] = aA01; coef[2] = aA11;
            coef[3] = fmaf(biA, own[0] / (float)HWPIX, -(aA00 * m0 + aA01 * m1));
            coef[4] = fmaf(biA, own[1] / (float)HWPIX, -(aA01 * m0 + aA11 * m1));
            coef[5] = aB00; coef[6] = aB01; coef[7] = aB11;
            coef[8] = fmaf(biB, own[2] / (float)HWPIX, -(aB00 * m0 + aB01 * m1));
            coef[9] = fmaf(biB, own[3] / (float)HWPIX, -(aB01 * m0 + aB11 * m1));
        }
    }
    __syncthreads();

    // ---- phase 2: normalize ----
    {
        const float a00 = coef[0], a01 = coef[1], a11 = coef[2];
        const float d0 = coef[3], d1 = coef[4];
        fx4* dst = (fx4*)out + (size_t)chA * F4_PER_CH;
#pragma unroll
        for (int i = 0; i < REGI; ++i)
            __builtin_nontemporal_store(affine2(va[i], a00, a01, a11, d0, d1),
                                        &dst[i * TPB + tid]);
#pragma unroll
        for (int i = 0; i < LDSI; ++i) {
            fx4 t = lcache[i * TPB + tid];
            __builtin_nontemporal_store(affine2(t, a00, a01, a11, d0, d1),
                                        &dst[(REGI + i) * TPB + tid]);
        }
#pragma unroll
        for (int i = REGI + LDSI; i < ITERS; ++i) {
            fx4 t = srcA[i * TPB + tid];   // L3 hit (normal-loaded in phase 1)
            __builtin_nontemporal_store(affine2(t, a00, a01, a11, d0, d1),
                                        &dst[i * TPB + tid]);
        }
    }
    {
        const float a00 = coef[5], a01 = coef[6], a11 = coef[7];
        const float d0 = coef[8], d1 = coef[9];
        fx4* dst = (fx4*)out + (size_t)(chA + 1) * F4_PER_CH;
#pragma unroll
        for (int i = 0; i < REGI; ++i)
            __builtin_nontemporal_store(affine2(vb[i], a00, a01, a11, d0, d1),
                                        &dst[i * TPB + tid]);
#pragma unroll
        for (int i = 0; i < LDSI; ++i) {
            fx4 t = lcache[(LDSI + i) * TPB + tid];
            __builtin_nontemporal_store(affine2(t, a00, a01, a11, d0, d1),
                                        &dst[(REGI + i) * TPB + tid]);
        }
#pragma unroll
        for (int i = REGI + LDSI; i < ITERS; ++i) {
            fx4 t = srcB[i * TPB + tid];
            __builtin_nontemporal_store(affine2(t, a00, a01, a11, d0, d1),
                                        &dst[i * TPB + tid]);
        }
    }
}

// ---------------- fallback: proven two-kernel path (R3, 64.4 us) ------------
__global__ __launch_bounds__(TPB) void gn_stats(const float* __restrict__ x,
                                                float* __restrict__ partials) {
    const int blk = blockIdx.x;
    const int sp  = blk % SPLIT;
    const int bc  = blk / SPLIT;
    const int CHUNK = F4_PER_CH / SPLIT;   // 2048
    const fx4* base = (const fx4*)x + (size_t)bc * F4_PER_CH + (size_t)sp * CHUNK;
    const int tid = threadIdx.x;

    float s0 = 0.f, s1 = 0.f, sxx = 0.f, sxy = 0.f, syy = 0.f;
#pragma unroll
    for (int i = 0; i < CHUNK / TPB; ++i)
        acc5(s0, s1, sxx, sxy, syy, base[tid + i * TPB]);
#pragma unroll
    for (int off = 32; off > 0; off >>= 1) {
        s0 += __shfl_down(s0, off);  s1 += __shfl_down(s1, off);
        sxx += __shfl_down(sxx, off); sxy += __shfl_down(sxy, off);
        syy += __shfl_down(syy, off);
    }
    __shared__ float red[4][5];
    const int wave = tid >> 6, lane = tid & 63;
    if (lane == 0) {
        red[wave][0] = s0; red[wave][1] = s1; red[wave][2] = sxx;
        red[wave][3] = sxy; red[wave][4] = syy;
    }
    __syncthreads();
    if (tid == 0) {
        float r0 = 0.f, r1 = 0.f, r2 = 0.f, r3 = 0.f, r4 = 0.f;
#pragma unroll
        for (int w = 0; w < 4; ++w) {
            r0 += red[w][0]; r1 += red[w][1]; r2 += red[w][2];
            r3 += red[w][3]; r4 += red[w][4];
        }
        float* p = partials + (size_t)(bc * SPLIT + sp) * 5;
        p[0] = r0; p[1] = r1; p[2] = r2; p[3] = r3; p[4] = r4;
    }
}

__global__ __launch_bounds__(TPB) void gn_norm(const float* __restrict__ x,
                                               const float* __restrict__ partials,
                                               const float* __restrict__ scale,
                                               const float* __restrict__ bias,
                                               float* __restrict__ out) {
    const int blk = blockIdx.x;
    const int sp  = blk % SPLIT;
    const int bc  = blk / SPLIT;
    const int c   = bc % CH;
    const int b   = bc / CH;
    const int g   = c / CPG;
    const int cig = c % CPG;

    const int CHUNK = F4_PER_CH / SPLIT;
    const fx4* src = (const fx4*)x + (size_t)bc * F4_PER_CH + (size_t)sp * CHUNK;
    fx4*       dst = (fx4*)out     + (size_t)bc * F4_PER_CH + (size_t)sp * CHUNK;
    const int tid = threadIdx.x;
    const int PER_THREAD = CHUNK / TPB;

    fx4 v[PER_THREAD];
#pragma unroll
    for (int i = 0; i < PER_THREAD; ++i) v[i] = src[tid + i * TPB];

    __shared__ float coef[5];
    if (tid < 32) {
        const float* p = partials +
            ((size_t)(b * CH + g * CPG + (tid >> 2)) * SPLIT + (tid & 3)) * 5;
        float p0 = p[0], p1 = p[1], p2 = p[2], p3 = p[3], p4 = p[4];
        const bool mine = (tid >> 2) == cig;
        float q0 = mine ? p0 : 0.f, q1 = mine ? p1 : 0.f;
#pragma unroll
        for (int off = 16; off > 0; off >>= 1) {
            p0 += __shfl_xor(p0, off, 32); p1 += __shfl_xor(p1, off, 32);
            p2 += __shfl_xor(p2, off, 32); p3 += __shfl_xor(p3, off, 32);
            p4 += __shfl_xor(p4, off, 32);
            q0 += __shfl_xor(q0, off, 32); q1 += __shfl_xor(q1, off, 32);
        }
        if (tid == 0) {
            float m0, m1, w00, w01, w11;
            solve_w(p0, p1, p2, p3, p4, (float)(CPG * HWPIX), m0, m1, w00, w01, w11);
            const float sc = scale[c], bi = bias[c];
            const float a00 = sc * w00, a01 = sc * w01, a11 = sc * w11;
            coef[0] = a00; coef[1] = a01; coef[2] = a11;
            coef[3] = fmaf(bi, q0 / (float)HWPIX, -(a00 * m0 + a01 * m1));
            coef[4] = fmaf(bi, q1 / (float)HWPIX, -(a01 * m0 + a11 * m1));
        }
    }
    __syncthreads();
    const float a00 = coef[0], a01 = coef[1], a11 = coef[2];
    const float d0 = coef[3], d1 = coef[4];
#pragma unroll
    for (int i = 0; i < PER_THREAD; ++i)
        __builtin_nontemporal_store(affine2(v[i], a00, a01, a11, d0, d1),
                                    &dst[tid + i * TPB]);
}

extern "C" void kernel_launch(void* const* d_in, const int* in_sizes, int n_in,
                              void* d_out, int out_size, void* d_ws, size_t ws_size,
                              hipStream_t stream) {
    const float* x     = (const float*)d_in[0];
    const float* scale = (const float*)d_in[1];
    const float* bias  = (const float*)d_in[2];
    float* out      = (float*)d_out;
    float* partials = (float*)d_ws;

    // host-only queries (run at capture time, never replayed)
    bool coop_ok = false;
    int dev = 0;
    if (hipGetDevice(&dev) == hipSuccess) {
        int has_coop = 0, ncu = 0, nblk_per_cu = 0;
        hipDeviceGetAttribute(&has_coop, hipDeviceAttributeCooperativeLaunch, dev);
        hipDeviceGetAttribute(&ncu, hipDeviceAttributeMultiprocessorCount, dev);
        hipOccupancyMaxActiveBlocksPerMultiprocessor(&nblk_per_cu, gn_fused2, TPB, 0);
        if (has_coop && (long)nblk_per_cu * ncu >= NBLK2) {
            void* args[] = {(void*)&x, (void*)&scale, (void*)&bias,
                            (void*)&partials, (void*)&out};
            hipError_t e = hipLaunchCooperativeKernel((const void*)gn_fused2,
                                                      dim3(NBLK2), dim3(TPB),
                                                      args, 0, stream);
            coop_ok = (e == hipSuccess);
        }
    }
    if (!coop_ok) {
        gn_stats<<<BATCH * CH * SPLIT, TPB, 0, stream>>>(x, partials);
        gn_norm<<<BATCH * CH * SPLIT, TPB, 0, stream>>>(x, partials, scale, bias, out);
    }
}